// Round 1
// baseline (2940.479 us; speedup 1.0000x reference)
//
#include <hip/hip_runtime.h>
#include <math.h>

#define B_ 4
#define S_ 2048
#define D_ 1024
#define M_ (B_*S_)   // 8192 rows total across batch

// ---------------------------------------------------------------------------
// GEMM: C[M,N] = op(A[M,K] @ W[K,N] + bias[N]); op = cos if DO_COS.
// 64x64 tile per block, K chunks of 16. A staged TRANSPOSED in LDS ([k][m])
// so both inner-loop fragment reads are contiguous float4 (ds_read_b128).
// Pad 68 floats/row: lane stride patterns give <=2-way bank aliasing (free).
// ---------------------------------------------------------------------------
template<int DO_COS>
__global__ __launch_bounds__(256)
void gemm_bias_k(const float* __restrict__ A, const float* __restrict__ W,
                 const float* __restrict__ bias, float* __restrict__ C) {
    const int K = D_, N = D_;
    __shared__ float As[16][68];   // [k][m]
    __shared__ float Ws[16][68];   // [k][n]
    const int tid = threadIdx.x;
    const int tx = tid & 15, ty = tid >> 4;
    const int m0 = blockIdx.y * 64, n0 = blockIdx.x * 64;

    const int ar = tid >> 2;            // 0..63 (m within tile)
    const int ac = (tid & 3) * 4;       // 0,4,8,12 (k within chunk)
    const int wr = tid >> 4;            // 0..15 (k within chunk)
    const int wc = (tid & 15) * 4;      // n within tile

    float acc[4][4] = {};

    for (int kc = 0; kc < K; kc += 16) {
        const float4 av = *(const float4*)&A[(size_t)(m0 + ar) * K + kc + ac];
        const float4 wv = *(const float4*)&W[(size_t)(kc + wr) * N + n0 + wc];
        As[ac+0][ar] = av.x; As[ac+1][ar] = av.y;
        As[ac+2][ar] = av.z; As[ac+3][ar] = av.w;
        *(float4*)&Ws[wr][wc] = wv;
        __syncthreads();
        #pragma unroll
        for (int kk = 0; kk < 16; ++kk) {
            const float4 a = *(const float4*)&As[kk][ty*4];
            const float4 b = *(const float4*)&Ws[kk][tx*4];
            const float ai[4] = {a.x, a.y, a.z, a.w};
            const float bi[4] = {b.x, b.y, b.z, b.w};
            #pragma unroll
            for (int i = 0; i < 4; ++i)
                #pragma unroll
                for (int j = 0; j < 4; ++j)
                    acc[i][j] += ai[i] * bi[j];
        }
        __syncthreads();
    }

    #pragma unroll
    for (int i = 0; i < 4; ++i) {
        const size_t m = (size_t)(m0 + ty*4 + i);
        float4 v;
        float* vp = (float*)&v;
        #pragma unroll
        for (int j = 0; j < 4; ++j) {
            float t = acc[i][j] + bias[n0 + tx*4 + j];
            if (DO_COS) t = cosf(t);
            vp[j] = t;
        }
        *(float4*)&C[m * N + n0 + tx*4] = v;
    }
}

// ---------------------------------------------------------------------------
// Flash-style attention: out[b,q,:] = softmax_k(Q[b,q,:].Khat[b,k,:]) @ V
// Block = 256 threads handles 16 queries of one batch. Keys processed in
// tiles of 64, D in chunks of 64 (Q/Khat staged in LDS, 2q x 2k register
// micro-tile). Online softmax state per row. O accumulator in registers:
// thread t owns output columns [4t, 4t+4) for all 16 queries (64 VGPRs).
// V is read directly from global (L2/L3 resident: 8MB/batch, reused by
// 128 blocks).
// ---------------------------------------------------------------------------
#define TQ 16
#define TK 64
#define DCH 64

__global__ __launch_bounds__(256)
void attn_k(const float* __restrict__ Q, const float* __restrict__ Kh,
            const float* __restrict__ V, float* __restrict__ O) {
    __shared__ float Qs[TQ][DCH+4];
    __shared__ float Ks[TK][DCH+4];
    __shared__ float Ps[TQ][TK+4];
    __shared__ float mrow[TQ], lrow[TQ], arow[TQ];

    const int tid = threadIdx.x;
    const int b  = blockIdx.y;
    const int q0 = blockIdx.x * TQ;
    const float* Qb = Q  + ((size_t)b * S_ + q0) * D_;
    const float* Kb = Kh + (size_t)b * S_ * D_;
    const float* Vb = V  + (size_t)b * S_ * D_;
    float*       Ob = O  + ((size_t)b * S_ + q0) * D_;

    const int qp = tid >> 5;          // 0..7  -> q rows {2qp, 2qp+1}
    const int kp = tid & 31;          // 0..31 -> k cols {2kp, 2kp+1}
    const int qr = qp * 2, kr = kp * 2;

    const int sr = tid >> 4;          // staging row 0..15
    const int sc = (tid & 15) * 4;    // staging col

    const int d0 = tid * 4;           // owned output columns

    float Oa[TQ][4];
    #pragma unroll
    for (int q = 0; q < TQ; ++q) { Oa[q][0]=0.f; Oa[q][1]=0.f; Oa[q][2]=0.f; Oa[q][3]=0.f; }
    if (tid < TQ) { mrow[tid] = -3e38f; lrow[tid] = 0.f; }
    __syncthreads();

    for (int k0 = 0; k0 < S_; k0 += TK) {
        float s00=0.f, s01=0.f, s10=0.f, s11=0.f;
        for (int dc = 0; dc < D_; dc += DCH) {
            // stage Q chunk (16x64): one float4 per thread
            *(float4*)&Qs[sr][sc] = *(const float4*)&Qb[(size_t)sr * D_ + dc + sc];
            // stage Khat chunk (64x64): four float4 per thread
            #pragma unroll
            for (int i = 0; i < 4; ++i) {
                const int idx = i * 256 + tid;
                const int r = idx >> 4, c = (idx & 15) * 4;
                *(float4*)&Ks[r][c] = *(const float4*)&Kb[(size_t)(k0 + r) * D_ + dc + c];
            }
            __syncthreads();
            #pragma unroll
            for (int d4 = 0; d4 < DCH; d4 += 4) {
                const float4 qa = *(const float4*)&Qs[qr][d4];
                const float4 qb = *(const float4*)&Qs[qr+1][d4];
                const float4 ka = *(const float4*)&Ks[kr][d4];
                const float4 kb = *(const float4*)&Ks[kr+1][d4];
                s00 += qa.x*ka.x + qa.y*ka.y + qa.z*ka.z + qa.w*ka.w;
                s01 += qa.x*kb.x + qa.y*kb.y + qa.z*kb.z + qa.w*kb.w;
                s10 += qb.x*ka.x + qb.y*ka.y + qb.z*ka.z + qb.w*ka.w;
                s11 += qb.x*kb.x + qb.y*kb.y + qb.z*kb.z + qb.w*kb.w;
            }
            __syncthreads();
        }
        Ps[qr  ][kr] = s00; Ps[qr  ][kr+1] = s01;
        Ps[qr+1][kr] = s10; Ps[qr+1][kr+1] = s11;
        __syncthreads();

        // online softmax: 16 lanes cooperate per row
        {
            const int row = tid >> 4, l16 = tid & 15;
            float mx = -3e38f;
            #pragma unroll
            for (int j = 0; j < 4; ++j) mx = fmaxf(mx, Ps[row][l16*4 + j]);
            #pragma unroll
            for (int off = 1; off < 16; off <<= 1) mx = fmaxf(mx, __shfl_xor(mx, off));
            const float m_old = mrow[row];
            const float m_new = fmaxf(m_old, mx);
            float sum = 0.f;
            #pragma unroll
            for (int j = 0; j < 4; ++j) {
                const float p = __expf(Ps[row][l16*4 + j] - m_new);
                Ps[row][l16*4 + j] = p;
                sum += p;
            }
            #pragma unroll
            for (int off = 1; off < 16; off <<= 1) sum += __shfl_xor(sum, off);
            if (l16 == 0) {
                const float al = __expf(m_old - m_new);
                arow[row] = al;
                lrow[row] = lrow[row] * al + sum;
                mrow[row] = m_new;
            }
        }
        __syncthreads();

        // rescale O by alpha, then accumulate P @ V (V streamed from global)
        #pragma unroll
        for (int q = 0; q < TQ; ++q) {
            const float al = arow[q];
            Oa[q][0]*=al; Oa[q][1]*=al; Oa[q][2]*=al; Oa[q][3]*=al;
        }
        for (int k = 0; k < TK; ++k) {
            const float4 v = *(const float4*)&Vb[(size_t)(k0 + k) * D_ + d0];
            #pragma unroll
            for (int q = 0; q < TQ; ++q) {
                const float p = Ps[q][k];
                Oa[q][0] += p * v.x; Oa[q][1] += p * v.y;
                Oa[q][2] += p * v.z; Oa[q][3] += p * v.w;
            }
        }
        __syncthreads();
    }

    #pragma unroll
    for (int q = 0; q < TQ; ++q) {
        const float inv = 1.0f / lrow[q];
        float4 v;
        v.x = Oa[q][0]*inv; v.y = Oa[q][1]*inv;
        v.z = Oa[q][2]*inv; v.w = Oa[q][3]*inv;
        *(float4*)&Ob[(size_t)q * D_ + d0] = v;
    }
}

// ---------------------------------------------------------------------------
extern "C" void kernel_launch(void* const* d_in, const int* in_sizes, int n_in,
                              void* d_out, int out_size, void* d_ws, size_t ws_size,
                              hipStream_t stream) {
    const float* x  = (const float*)d_in[0];
    const float* y  = (const float*)d_in[1];
    const float* Wq = (const float*)d_in[2];
    const float* bq = (const float*)d_in[3];
    const float* Wk = (const float*)d_in[4];
    const float* bk = (const float*)d_in[5];
    const float* Wv = (const float*)d_in[6];
    const float* bv = (const float*)d_in[7];
    const float* Wr = (const float*)d_in[8];
    const float* br = (const float*)d_in[9];
    float* out = (float*)d_out;

    // workspace layout: 3 buffers of 8192x1024 fp32 = 32 MB each (96 MB)
    const size_t n = (size_t)M_ * D_;
    float* bufQ  = (float*)d_ws;        // holds K first, later overwritten by Q
    float* bufKh = bufQ + n;
    float* bufV  = bufKh + n;

    dim3 gg(D_/64, M_/64), bb(256);
    gemm_bias_k<0><<<gg, bb, 0, stream>>>(y,    Wk, bk, bufQ);   // K = y@Wk+bk
    gemm_bias_k<1><<<gg, bb, 0, stream>>>(bufQ, Wr, br, bufKh);  // Khat = cos(K@Wr+br)
    gemm_bias_k<0><<<gg, bb, 0, stream>>>(x,    Wq, bq, bufQ);   // Q = x@Wq+bq (reuse buf)
    gemm_bias_k<0><<<gg, bb, 0, stream>>>(y,    Wv, bv, bufV);   // V = y@Wv+bv

    dim3 ga(S_/TQ, B_);
    attn_k<<<ga, bb, 0, stream>>>(bufQ, bufKh, bufV, out);
}

// Round 3
// 1258.547 us; speedup vs baseline: 2.3364x; 2.3364x over previous
//
#include <hip/hip_runtime.h>
#include <hip/hip_bf16.h>
#include <math.h>

#define B_ 4
#define S_ 2048
#define D_ 1024
#define M_ (B_*S_)   // 8192 rows total across batch
#define MBYTE (1024ull*1024ull)

typedef __attribute__((ext_vector_type(8))) _Float16 f16x8;  // 8 f16 = 4 VGPRs (MFMA A/B frag)
typedef __attribute__((ext_vector_type(4))) float f32x4;     // MFMA C/D frag

__device__ inline unsigned short f2h(float f) {
    union { _Float16 h; unsigned short u; } x;
    x.h = (_Float16)f;   // RTE
    return x.u;
}

__device__ inline void gload16(const unsigned short* g, unsigned short* l) {
    __builtin_amdgcn_global_load_lds(
        (const __attribute__((address_space(1))) unsigned int*)g,
        (__attribute__((address_space(3))) unsigned int*)l, 16, 0, 0);
}

// ---------------------------------------------------------------------------
// fp32 projection GEMM (round-1 structure): C = op(A@W + bias).
// OUT_F16: write fp16 row-major. DO_COS: apply cosf.
// ---------------------------------------------------------------------------
template<int DO_COS, int OUT_F16>
__global__ __launch_bounds__(256)
void gemm_bias_k(const float* __restrict__ A, const float* __restrict__ W,
                 const float* __restrict__ bias, void* __restrict__ Cv) {
    const int K = D_, N = D_;
    __shared__ float As[16][68];   // [k][m]
    __shared__ float Ws[16][68];   // [k][n]
    const int tid = threadIdx.x;
    const int tx = tid & 15, ty = tid >> 4;
    const int m0 = blockIdx.y * 64, n0 = blockIdx.x * 64;

    const int ar = tid >> 2;            // m within tile
    const int ac = (tid & 3) * 4;       // k within chunk
    const int wr = tid >> 4;            // k within chunk
    const int wc = (tid & 15) * 4;      // n within tile

    float acc[4][4] = {};

    for (int kc = 0; kc < K; kc += 16) {
        const float4 av = *(const float4*)&A[(size_t)(m0 + ar) * K + kc + ac];
        const float4 wv = *(const float4*)&W[(size_t)(kc + wr) * N + n0 + wc];
        As[ac+0][ar] = av.x; As[ac+1][ar] = av.y;
        As[ac+2][ar] = av.z; As[ac+3][ar] = av.w;
        *(float4*)&Ws[wr][wc] = wv;
        __syncthreads();
        #pragma unroll
        for (int kk = 0; kk < 16; ++kk) {
            const float4 a = *(const float4*)&As[kk][ty*4];
            const float4 b = *(const float4*)&Ws[kk][tx*4];
            const float ai[4] = {a.x, a.y, a.z, a.w};
            const float bi[4] = {b.x, b.y, b.z, b.w};
            #pragma unroll
            for (int i = 0; i < 4; ++i)
                #pragma unroll
                for (int j = 0; j < 4; ++j)
                    acc[i][j] += ai[i] * bi[j];
        }
        __syncthreads();
    }

    #pragma unroll
    for (int i = 0; i < 4; ++i) {
        const size_t m = (size_t)(m0 + ty*4 + i);
        float t[4];
        #pragma unroll
        for (int j = 0; j < 4; ++j) {
            t[j] = acc[i][j] + bias[n0 + tx*4 + j];
            if (DO_COS) t[j] = cosf(t[j]);
        }
        if (OUT_F16) {
            unsigned short* C = (unsigned short*)Cv;
            ushort4 o;
            o.x = f2h(t[0]); o.y = f2h(t[1]); o.z = f2h(t[2]); o.w = f2h(t[3]);
            *(ushort4*)&C[m * N + n0 + tx*4] = o;
        } else {
            float* C = (float*)Cv;
            float4 v; v.x=t[0]; v.y=t[1]; v.z=t[2]; v.w=t[3];
            *(float4*)&C[m * N + n0 + tx*4] = v;
        }
    }
}

// ---------------------------------------------------------------------------
// Transpose-cast: V fp32 [b][s][d] -> Vt fp16 [b][d][s]
// ---------------------------------------------------------------------------
__global__ __launch_bounds__(256)
void transpose_cast_k(const float* __restrict__ V, unsigned short* __restrict__ Vt) {
    __shared__ float t[64][65];
    const int tid = threadIdx.x;
    const int s0 = blockIdx.x*64, d0 = blockIdx.y*64, b = blockIdx.z;
    const float* Vb = V + (size_t)b*S_*D_;
    unsigned short* Vtb = Vt + (size_t)b*D_*S_;
    #pragma unroll
    for (int i = 0; i < 4; ++i) {
        const int c = i*256 + tid;
        const int row = c >> 4, col = (c & 15) * 4;
        const float4 v = *(const float4*)&Vb[(size_t)(s0+row)*D_ + d0+col];
        t[row][col]=v.x; t[row][col+1]=v.y; t[row][col+2]=v.z; t[row][col+3]=v.w;
    }
    __syncthreads();
    #pragma unroll
    for (int i = 0; i < 4; ++i) {
        const int c = i*256 + tid;
        const int d = c >> 4, s = (c & 15) * 4;
        ushort4 o;
        o.x = f2h(t[s  ][d]); o.y = f2h(t[s+1][d]);
        o.z = f2h(t[s+2][d]); o.w = f2h(t[s+3][d]);
        *(ushort4*)&Vtb[(size_t)(d0+d)*S_ + s0+s] = o;
    }
}

// ---------------------------------------------------------------------------
// m97-style fp16 MFMA GEMM: C[M][N] fp32 = A[M][K] @ Bt[N][K]^T  (fp16 in)
// 128x128 tile, BK=64, 4 waves in 2x2 (64x64 each, 4x4 of 16x16x32 MFMA).
// global_load_lds width=16 staging; z-batched via strides.
// ---------------------------------------------------------------------------
template<int Mv, int Nv, int Kv>
__global__ __launch_bounds__(256)
void gemm_bt_k(const unsigned short* __restrict__ A, const unsigned short* __restrict__ Bt,
               float* __restrict__ C, long sA, long sB, long sC) {
    __shared__ unsigned short As[128*64];
    __shared__ unsigned short Bs[128*64];
    const int tid = threadIdx.x;
    const unsigned short* Ab = A  + (size_t)blockIdx.z * sA;
    const unsigned short* Bb = Bt + (size_t)blockIdx.z * sB;
    float*               Cb = C  + (size_t)blockIdx.z * sC;
    const int m0 = blockIdx.y * 128, n0 = blockIdx.x * 128;
    const int lane = tid & 63, w = tid >> 6;
    const int mw = (w >> 1) * 64, nw = (w & 1) * 64;
    const int lr = lane & 15, lq = lane >> 4;

    const int crow = tid >> 3;          // staging row (0..31, +32/i)
    const int ccol = (tid & 7) * 8;     // staging chunk col (elems)

    f32x4 acc[4][4];
    #pragma unroll
    for (int i = 0; i < 4; ++i)
        #pragma unroll
        for (int j = 0; j < 4; ++j)
            acc[i][j] = (f32x4){0.f, 0.f, 0.f, 0.f};

    for (int kc = 0; kc < Kv; kc += 64) {
        #pragma unroll
        for (int i = 0; i < 4; ++i) {
            const int r = crow + i * 32;
            gload16(&Ab[(size_t)(m0 + r) * Kv + kc + ccol], &As[(size_t)(i*256 + tid) * 8]);
            gload16(&Bb[(size_t)(n0 + r) * Kv + kc + ccol], &Bs[(size_t)(i*256 + tid) * 8]);
        }
        __syncthreads();
        #pragma unroll
        for (int kk = 0; kk < 64; kk += 32) {
            f16x8 a[4], b[4];
            #pragma unroll
            for (int i = 0; i < 4; ++i)
                a[i] = *(const f16x8*)&As[(mw + i*16 + lr) * 64 + kk + lq*8];
            #pragma unroll
            for (int j = 0; j < 4; ++j)
                b[j] = *(const f16x8*)&Bs[(nw + j*16 + lr) * 64 + kk + lq*8];
            #pragma unroll
            for (int i = 0; i < 4; ++i)
                #pragma unroll
                for (int j = 0; j < 4; ++j)
                    acc[i][j] = __builtin_amdgcn_mfma_f32_16x16x32_f16(a[i], b[j], acc[i][j], 0, 0, 0);
        }
        __syncthreads();
    }

    // C/D layout (verified m89/m91, dtype-independent): col=lane&15, row=(lane>>4)*4+reg
    #pragma unroll
    for (int i = 0; i < 4; ++i)
        #pragma unroll
        for (int j = 0; j < 4; ++j) {
            const int row = m0 + mw + i*16 + lq*4;
            const int col = n0 + nw + j*16 + lr;
            #pragma unroll
            for (int r = 0; r < 4; ++r)
                Cb[(size_t)(row + r) * Nv + col] = acc[i][j][r];
        }
}

// ---------------------------------------------------------------------------
// Row softmax: S fp32 [S_] per row -> normalized P fp16. One block per row.
// ---------------------------------------------------------------------------
__global__ __launch_bounds__(256)
void softmax_k(const float* __restrict__ S, unsigned short* __restrict__ P) {
    __shared__ float red[8];
    const int tid = threadIdx.x;
    const int lane = tid & 63, w = tid >> 6;
    const float* row = S + (size_t)blockIdx.x * S_;

    const float4 v0 = *(const float4*)&row[tid*8];
    const float4 v1 = *(const float4*)&row[tid*8 + 4];
    float e[8] = {v0.x, v0.y, v0.z, v0.w, v1.x, v1.y, v1.z, v1.w};

    float mx = e[0];
    #pragma unroll
    for (int j = 1; j < 8; ++j) mx = fmaxf(mx, e[j]);
    #pragma unroll
    for (int off = 1; off < 64; off <<= 1) mx = fmaxf(mx, __shfl_xor(mx, off));
    if (lane == 0) red[w] = mx;
    __syncthreads();
    mx = fmaxf(fmaxf(red[0], red[1]), fmaxf(red[2], red[3]));

    float sum = 0.f;
    #pragma unroll
    for (int j = 0; j < 8; ++j) { e[j] = __expf(e[j] - mx); sum += e[j]; }
    #pragma unroll
    for (int off = 1; off < 64; off <<= 1) sum += __shfl_xor(sum, off);
    if (lane == 0) red[4 + w] = sum;
    __syncthreads();
    const float inv = 1.0f / (red[4] + red[5] + red[6] + red[7]);

    ushort4 o0, o1;
    o0.x = f2h(e[0]*inv); o0.y = f2h(e[1]*inv); o0.z = f2h(e[2]*inv); o0.w = f2h(e[3]*inv);
    o1.x = f2h(e[4]*inv); o1.y = f2h(e[5]*inv); o1.z = f2h(e[6]*inv); o1.w = f2h(e[7]*inv);
    *(ushort4*)&P[(size_t)blockIdx.x * S_ + tid*8]     = o0;
    *(ushort4*)&P[(size_t)blockIdx.x * S_ + tid*8 + 4] = o1;
}

// ---------------------------------------------------------------------------
extern "C" void kernel_launch(void* const* d_in, const int* in_sizes, int n_in,
                              void* d_out, int out_size, void* d_ws, size_t ws_size,
                              hipStream_t stream) {
    const float* x  = (const float*)d_in[0];
    const float* y  = (const float*)d_in[1];
    const float* Wq = (const float*)d_in[2];
    const float* bq = (const float*)d_in[3];
    const float* Wk = (const float*)d_in[4];
    const float* bk = (const float*)d_in[5];
    const float* Wv = (const float*)d_in[6];
    const float* bv = (const float*)d_in[7];
    const float* Wr = (const float*)d_in[8];
    const float* br = (const float*)d_in[9];
    float* out = (float*)d_out;

    // Workspace (96 MB total, round-1-proven):
    //  [ 0,16) Vt fp16 [B][D][S]
    //  [16,48) temp V fp32 -> temp K fp32 -> P fp16 (all batches)
    //  [48,64) Q fp16
    //  [64,80) Khat fp16
    //  [80,96) S fp32 (one batch at a time)
    char* wsb = (char*)d_ws;
    unsigned short* Vt = (unsigned short*)(wsb + 0*MBYTE);
    float*          Vf = (float*)         (wsb + 16*MBYTE);
    float*          Kf = (float*)         (wsb + 16*MBYTE);
    unsigned short* Pb = (unsigned short*)(wsb + 16*MBYTE);
    unsigned short* Qb = (unsigned short*)(wsb + 48*MBYTE);
    unsigned short* Kh = (unsigned short*)(wsb + 64*MBYTE);
    float*          Sb = (float*)         (wsb + 80*MBYTE);

    dim3 gg(D_/64, M_/64), bb(256);
    // 1. V = y@Wv+bv (fp32)
    gemm_bias_k<0,0><<<gg, bb, 0, stream>>>(y, Wv, bv, (void*)Vf);
    // 2. Vt = transpose(V) as fp16
    transpose_cast_k<<<dim3(S_/64, D_/64, B_), bb, 0, stream>>>(Vf, Vt);
    // 3. K = y@Wk+bk (fp32)  (overwrites dead V)
    gemm_bias_k<0,0><<<gg, bb, 0, stream>>>(y, Wk, bk, (void*)Kf);
    // 4. Khat = cos(K@Wr+br) (fp16)
    gemm_bias_k<1,1><<<gg, bb, 0, stream>>>(Kf, Wr, br, (void*)Kh);
    // 5. Q = x@Wq+bq (fp16)
    gemm_bias_k<0,1><<<gg, bb, 0, stream>>>(x, Wq, bq, (void*)Qb);

    // 6. per batch: scores (MFMA) + softmax -> P
    for (int b = 0; b < B_; ++b) {
        gemm_bt_k<S_, S_, D_><<<dim3(S_/128, S_/128, 1), bb, 0, stream>>>(
            Qb + (size_t)b*S_*D_, Kh + (size_t)b*S_*D_, Sb, 0, 0, 0);
        softmax_k<<<dim3(S_), bb, 0, stream>>>(Sb, Pb + (size_t)b*S_*S_);
    }
    // 7. out = P @ V  (z-batched MFMA GEMM)
    gemm_bt_k<S_, D_, S_><<<dim3(D_/128, S_/128, B_), bb, 0, stream>>>(
        Pb, Vt, out, (long)S_*S_, (long)D_*S_, (long)S_*D_);
}

// Round 4
// 581.894 us; speedup vs baseline: 5.0533x; 2.1628x over previous
//
#include <hip/hip_runtime.h>
#include <hip/hip_bf16.h>
#include <math.h>

#define B_ 4
#define S_ 2048
#define D_ 1024
#define M_ (B_*S_)   // 8192 rows total across batch
#define MBYTE (1024ull*1024ull)

typedef __attribute__((ext_vector_type(8))) _Float16 f16x8;  // 8 f16 = 4 VGPRs (MFMA A/B frag)
typedef __attribute__((ext_vector_type(4))) float f32x4;     // MFMA C/D frag
typedef unsigned short us;

__device__ inline us f2h(float f) {
    union { _Float16 h; us u; } x;
    x.h = (_Float16)f;   // RTE
    return x.u;
}
__device__ inline float h2f(us u) {
    union { us u; _Float16 h; } x; x.u = u;
    return (float)x.h;
}

__device__ inline void gload16(const us* g, us* l) {
    __builtin_amdgcn_global_load_lds(
        (const __attribute__((address_space(1))) unsigned int*)g,
        (__attribute__((address_space(3))) unsigned int*)l, 16, 0, 0);
}

// ---------------------------------------------------------------------------
// Split cast: f32 -> hi fp16 (+ lo fp16 residual if DO_LO). 4 elems/thread.
// ---------------------------------------------------------------------------
template<int DO_LO>
__global__ __launch_bounds__(256)
void cast2_k(const float* __restrict__ in, us* __restrict__ hi, us* __restrict__ lo) {
    const size_t i = ((size_t)blockIdx.x * 256 + threadIdx.x) * 4;
    const float4 v = *(const float4*)&in[i];
    ushort4 h;
    h.x = f2h(v.x); h.y = f2h(v.y); h.z = f2h(v.z); h.w = f2h(v.w);
    *(ushort4*)&hi[i] = h;
    if (DO_LO) {
        ushort4 l;
        l.x = f2h(v.x - h2f(h.x)); l.y = f2h(v.y - h2f(h.y));
        l.z = f2h(v.z - h2f(h.z)); l.w = f2h(v.w - h2f(h.w));
        *(ushort4*)&lo[i] = l;
    }
}

// ---------------------------------------------------------------------------
// Weight transpose + split cast: W fp32 [K][N] -> Wt1(,Wt2) fp16 [N][K].
// ---------------------------------------------------------------------------
template<int DO_LO>
__global__ __launch_bounds__(256)
void wsplit_k(const float* __restrict__ W, us* __restrict__ Wt1, us* __restrict__ Wt2) {
    __shared__ float t[64][65];
    const int tid = threadIdx.x;
    const int k0 = blockIdx.x*64, n0 = blockIdx.y*64;
    #pragma unroll
    for (int i = 0; i < 4; ++i) {
        const int c = i*256 + tid;
        const int row = c >> 4, col = (c & 15) * 4;
        const float4 v = *(const float4*)&W[(size_t)(k0+row)*D_ + n0+col];
        t[row][col]=v.x; t[row][col+1]=v.y; t[row][col+2]=v.z; t[row][col+3]=v.w;
    }
    __syncthreads();
    #pragma unroll
    for (int i = 0; i < 4; ++i) {
        const int c = i*256 + tid;
        const int n = c >> 4, k = (c & 15) * 4;
        float f[4] = { t[k][n], t[k+1][n], t[k+2][n], t[k+3][n] };
        ushort4 h;
        h.x=f2h(f[0]); h.y=f2h(f[1]); h.z=f2h(f[2]); h.w=f2h(f[3]);
        *(ushort4*)&Wt1[(size_t)(n0+n)*D_ + k0+k] = h;
        if (DO_LO) {
            ushort4 l;
            l.x=f2h(f[0]-h2f(h.x)); l.y=f2h(f[1]-h2f(h.y));
            l.z=f2h(f[2]-h2f(h.z)); l.w=f2h(f[3]-h2f(h.w));
            *(ushort4*)&Wt2[(size_t)(n0+n)*D_ + k0+k] = l;
        }
    }
}

// ---------------------------------------------------------------------------
// V transpose: fp16 [b][s][d] -> fp16 [b][d][s]
// ---------------------------------------------------------------------------
__global__ __launch_bounds__(256)
void vtrans_k(const us* __restrict__ V, us* __restrict__ Vt) {
    __shared__ us t[64][68];
    const int tid = threadIdx.x;
    const int s0 = blockIdx.x*64, d0 = blockIdx.y*64, b = blockIdx.z;
    const us* Vb  = V  + (size_t)b*S_*D_;
    us*       Vtb = Vt + (size_t)b*D_*S_;
    #pragma unroll
    for (int i = 0; i < 4; ++i) {
        const int c = i*256 + tid;
        const int row = c >> 4, col = (c & 15) * 4;
        *(ushort4*)&t[row][col] = *(const ushort4*)&Vb[(size_t)(s0+row)*D_ + d0+col];
    }
    __syncthreads();
    #pragma unroll
    for (int i = 0; i < 4; ++i) {
        const int c = i*256 + tid;
        const int d = c >> 4, s = (c & 15) * 4;
        ushort4 o;
        o.x = t[s][d]; o.y = t[s+1][d]; o.z = t[s+2][d]; o.w = t[s+3][d];
        *(ushort4*)&Vtb[(size_t)(d0+d)*S_ + s0+s] = o;
    }
}

// ---------------------------------------------------------------------------
// fp16 MFMA GEMM: C[M][N] = A[M][K] @ Bt[N][K]^T, fp32 accumulate.
// 128x128 tile, BK=64, 4 waves 2x2, global_load_lds width-16 staging.
// SPLIT=1: A=A1+A2, B=B1+B2 (fp16 hi/lo); computes A1B1+A1B2+A2B1 (fp32-grade).
// EPI: 0 = fp32 store; 1 = f16(acc+bias); 2 = f16(cos(acc+bias));
//      3 = split f16 store of (acc+bias) into C,C2.
// ---------------------------------------------------------------------------
template<int Nv, int Kv, int SPLIT, int EPI>
__global__ __launch_bounds__(256)
void gemm_bt_k(const us* __restrict__ A1, const us* __restrict__ A2,
               const us* __restrict__ B1, const us* __restrict__ B2,
               const float* __restrict__ bias, void* __restrict__ Cv,
               us* __restrict__ C2, long sA, long sB, long sC) {
    __shared__ us As[(SPLIT?2:1)*128*64];
    __shared__ us Bs[(SPLIT?2:1)*128*64];
    us* As2 = As + 128*64;
    us* Bs2 = Bs + 128*64;
    const int tid = threadIdx.x;
    const us* A1b = A1 + (size_t)blockIdx.z * sA;
    const us* A2b = SPLIT ? A2 + (size_t)blockIdx.z * sA : nullptr;
    const us* B1b = B1 + (size_t)blockIdx.z * sB;
    const us* B2b = SPLIT ? B2 + (size_t)blockIdx.z * sB : nullptr;
    const int m0 = blockIdx.y * 128, n0 = blockIdx.x * 128;
    const int lane = tid & 63, w = tid >> 6;
    const int mw = (w >> 1) * 64, nw = (w & 1) * 64;
    const int lr = lane & 15, lq = lane >> 4;

    const int crow = tid >> 3;          // staging row (0..31, +32/i)
    const int ccol = (tid & 7) * 8;     // staging col chunk (elems)

    f32x4 acc[4][4];
    #pragma unroll
    for (int i = 0; i < 4; ++i)
        #pragma unroll
        for (int j = 0; j < 4; ++j)
            acc[i][j] = (f32x4){0.f, 0.f, 0.f, 0.f};

    for (int kc = 0; kc < Kv; kc += 64) {
        #pragma unroll
        for (int i = 0; i < 4; ++i) {
            const int r = crow + i * 32;
            gload16(&A1b[(size_t)(m0 + r) * Kv + kc + ccol], &As[(size_t)(i*256 + tid) * 8]);
            gload16(&B1b[(size_t)(n0 + r) * Kv + kc + ccol], &Bs[(size_t)(i*256 + tid) * 8]);
            if (SPLIT) {
                gload16(&A2b[(size_t)(m0 + r) * Kv + kc + ccol], &As2[(size_t)(i*256 + tid) * 8]);
                gload16(&B2b[(size_t)(n0 + r) * Kv + kc + ccol], &Bs2[(size_t)(i*256 + tid) * 8]);
            }
        }
        __syncthreads();
        #pragma unroll
        for (int kk = 0; kk < 64; kk += 32) {
            f16x8 a1[4], b1[4];
            #pragma unroll
            for (int i = 0; i < 4; ++i)
                a1[i] = *(const f16x8*)&As[(mw + i*16 + lr) * 64 + kk + lq*8];
            #pragma unroll
            for (int j = 0; j < 4; ++j)
                b1[j] = *(const f16x8*)&Bs[(nw + j*16 + lr) * 64 + kk + lq*8];
            if (SPLIT) {
                f16x8 a2[4], b2[4];
                #pragma unroll
                for (int i = 0; i < 4; ++i)
                    a2[i] = *(const f16x8*)&As2[(mw + i*16 + lr) * 64 + kk + lq*8];
                #pragma unroll
                for (int j = 0; j < 4; ++j)
                    b2[j] = *(const f16x8*)&Bs2[(nw + j*16 + lr) * 64 + kk + lq*8];
                #pragma unroll
                for (int i = 0; i < 4; ++i)
                    #pragma unroll
                    for (int j = 0; j < 4; ++j) {
                        acc[i][j] = __builtin_amdgcn_mfma_f32_16x16x32_f16(a2[i], b1[j], acc[i][j], 0, 0, 0);
                        acc[i][j] = __builtin_amdgcn_mfma_f32_16x16x32_f16(a1[i], b2[j], acc[i][j], 0, 0, 0);
                        acc[i][j] = __builtin_amdgcn_mfma_f32_16x16x32_f16(a1[i], b1[j], acc[i][j], 0, 0, 0);
                    }
            } else {
                #pragma unroll
                for (int i = 0; i < 4; ++i)
                    #pragma unroll
                    for (int j = 0; j < 4; ++j)
                        acc[i][j] = __builtin_amdgcn_mfma_f32_16x16x32_f16(a1[i], b1[j], acc[i][j], 0, 0, 0);
            }
        }
        __syncthreads();
    }

    // C/D layout (verified m89/m91, dtype-independent): col=lane&15, row=(lane>>4)*4+reg
    #pragma unroll
    for (int i = 0; i < 4; ++i)
        #pragma unroll
        for (int j = 0; j < 4; ++j) {
            const int row = m0 + mw + i*16 + lq*4;
            const int col = n0 + nw + j*16 + lr;
            const float bc = (EPI != 0) ? bias[col] : 0.f;
            #pragma unroll
            for (int r = 0; r < 4; ++r) {
                const size_t idx = (size_t)(row + r) * Nv + col;
                const float t = acc[i][j][r] + bc;
                if (EPI == 0) {
                    ((float*)Cv)[idx + (size_t)blockIdx.z * sC] = acc[i][j][r];
                } else if (EPI == 1) {
                    ((us*)Cv)[idx] = f2h(t);
                } else if (EPI == 2) {
                    ((us*)Cv)[idx] = f2h(cosf(t));
                } else {
                    const us h = f2h(t);
                    ((us*)Cv)[idx] = h;
                    C2[idx] = f2h(t - h2f(h));
                }
            }
        }
}

// ---------------------------------------------------------------------------
// Row softmax: S fp32 [S_] per row -> normalized P fp16. One block per row.
// ---------------------------------------------------------------------------
__global__ __launch_bounds__(256)
void softmax_k(const float* __restrict__ S, us* __restrict__ P) {
    __shared__ float red[8];
    const int tid = threadIdx.x;
    const int lane = tid & 63, w = tid >> 6;
    const float* row = S + (size_t)blockIdx.x * S_;

    const float4 v0 = *(const float4*)&row[tid*8];
    const float4 v1 = *(const float4*)&row[tid*8 + 4];
    float e[8] = {v0.x, v0.y, v0.z, v0.w, v1.x, v1.y, v1.z, v1.w};

    float mx = e[0];
    #pragma unroll
    for (int j = 1; j < 8; ++j) mx = fmaxf(mx, e[j]);
    #pragma unroll
    for (int off = 1; off < 64; off <<= 1) mx = fmaxf(mx, __shfl_xor(mx, off));
    if (lane == 0) red[w] = mx;
    __syncthreads();
    mx = fmaxf(fmaxf(red[0], red[1]), fmaxf(red[2], red[3]));

    float sum = 0.f;
    #pragma unroll
    for (int j = 0; j < 8; ++j) { e[j] = __expf(e[j] - mx); sum += e[j]; }
    #pragma unroll
    for (int off = 1; off < 64; off <<= 1) sum += __shfl_xor(sum, off);
    if (lane == 0) red[4 + w] = sum;
    __syncthreads();
    const float inv = 1.0f / (red[4] + red[5] + red[6] + red[7]);

    ushort4 o0, o1;
    o0.x = f2h(e[0]*inv); o0.y = f2h(e[1]*inv); o0.z = f2h(e[2]*inv); o0.w = f2h(e[3]*inv);
    o1.x = f2h(e[4]*inv); o1.y = f2h(e[5]*inv); o1.z = f2h(e[6]*inv); o1.w = f2h(e[7]*inv);
    *(ushort4*)&P[(size_t)blockIdx.x * S_ + tid*8]     = o0;
    *(ushort4*)&P[(size_t)blockIdx.x * S_ + tid*8 + 4] = o1;
}

// ---------------------------------------------------------------------------
extern "C" void kernel_launch(void* const* d_in, const int* in_sizes, int n_in,
                              void* d_out, int out_size, void* d_ws, size_t ws_size,
                              hipStream_t stream) {
    const float* x  = (const float*)d_in[0];
    const float* y  = (const float*)d_in[1];
    const float* Wq = (const float*)d_in[2];
    const float* bq = (const float*)d_in[3];
    const float* Wk = (const float*)d_in[4];
    const float* bk = (const float*)d_in[5];
    const float* Wv = (const float*)d_in[6];
    const float* bv = (const float*)d_in[7];
    const float* Wr = (const float*)d_in[8];
    const float* br = (const float*)d_in[9];
    float* out = (float*)d_out;

    // Workspace choreography (96 MB, proven size). Regions by phase:
    //  [ 0,16) K1            -> Vt
    //  [16,32) Wk1/Wk2, then Wr1/Wr2 -> xh -> Vh -> P(b0,b1)
    //  [32,48) y1                              -> P(b2,b3)
    //  [48,64) K2            -> Q
    //  [64,80) Kh
    //  [80,96) y2 -> Wq1/Wv1 -> S (per batch fp32)
    char* wsb = (char*)d_ws;
    us*    K1  = (us*)(wsb +  0*MBYTE);
    us*    Vt  = (us*)(wsb +  0*MBYTE);
    us*    Wk1 = (us*)(wsb + 16*MBYTE);
    us*    Wk2 = (us*)(wsb + 18*MBYTE);
    us*    Wr1 = (us*)(wsb + 16*MBYTE);
    us*    Wr2 = (us*)(wsb + 18*MBYTE);
    us*    xh  = (us*)(wsb + 16*MBYTE);
    us*    Vh  = (us*)(wsb + 16*MBYTE);
    us*    Pb  = (us*)(wsb + 16*MBYTE);
    us*    y1  = (us*)(wsb + 32*MBYTE);
    us*    K2  = (us*)(wsb + 48*MBYTE);
    us*    Qb  = (us*)(wsb + 48*MBYTE);
    us*    Kh  = (us*)(wsb + 64*MBYTE);
    us*    y2  = (us*)(wsb + 80*MBYTE);
    us*    Wq1 = (us*)(wsb + 80*MBYTE);
    us*    Wv1 = (us*)(wsb + 80*MBYTE);
    float* Sb  = (float*)(wsb + 80*MBYTE);

    const dim3 bb(256);
    const dim3 gcast(M_*D_/1024), gw(16,16), gproj(D_/128, M_/128);

    // --- K chain (split-fp16 = fp32-grade accuracy) ---
    cast2_k<1><<<gcast, bb, 0, stream>>>(y, y1, y2);
    wsplit_k<1><<<gw, bb, 0, stream>>>(Wk, Wk1, Wk2);
    gemm_bt_k<D_, D_, 1, 3><<<gproj, bb, 0, stream>>>(
        y1, y2, Wk1, Wk2, bk, (void*)K1, K2, 0, 0, 0);
    wsplit_k<1><<<gw, bb, 0, stream>>>(Wr, Wr1, Wr2);
    gemm_bt_k<D_, D_, 1, 2><<<gproj, bb, 0, stream>>>(
        K1, K2, Wr1, Wr2, br, (void*)Kh, nullptr, 0, 0, 0);

    // --- Q, V (plain fp16 MFMA) ---
    cast2_k<0><<<gcast, bb, 0, stream>>>(x, xh, nullptr);
    wsplit_k<0><<<gw, bb, 0, stream>>>(Wq, Wq1, nullptr);
    gemm_bt_k<D_, D_, 0, 1><<<gproj, bb, 0, stream>>>(
        xh, nullptr, Wq1, nullptr, bq, (void*)Qb, nullptr, 0, 0, 0);
    wsplit_k<0><<<gw, bb, 0, stream>>>(Wv, Wv1, nullptr);
    gemm_bt_k<D_, D_, 0, 1><<<gproj, bb, 0, stream>>>(
        y1, nullptr, Wv1, nullptr, bv, (void*)Vh, nullptr, 0, 0, 0);
    vtrans_k<<<dim3(S_/64, D_/64, B_), bb, 0, stream>>>(Vh, Vt);

    // --- attention core ---
    for (int b = 0; b < B_; ++b) {
        gemm_bt_k<S_, D_, 0, 0><<<dim3(S_/128, S_/128, 1), bb, 0, stream>>>(
            Qb + (size_t)b*S_*D_, nullptr, Kh + (size_t)b*S_*D_, nullptr,
            nullptr, (void*)Sb, nullptr, 0, 0, 0);
        softmax_k<<<dim3(S_), bb, 0, stream>>>(Sb, Pb + (size_t)b*S_*S_);
    }
    gemm_bt_k<D_, S_, 0, 0><<<dim3(D_/128, S_/128, B_), bb, 0, stream>>>(
        Pb, nullptr, Vt, nullptr, nullptr, (void*)out, nullptr,
        (long)S_*S_, (long)D_*S_, (long)S_*D_);
}

// Round 5
// 559.863 us; speedup vs baseline: 5.2521x; 1.0394x over previous
//
#include <hip/hip_runtime.h>
#include <hip/hip_bf16.h>
#include <math.h>

#define B_ 4
#define S_ 2048
#define D_ 1024
#define M_ (B_*S_)   // 8192 rows total across batch
#define MBYTE (1024ull*1024ull)

typedef __attribute__((ext_vector_type(8))) _Float16 f16x8;  // 8 f16 = 4 VGPRs (MFMA A/B frag)
typedef __attribute__((ext_vector_type(4))) float f32x4;     // MFMA C/D frag
typedef __attribute__((ext_vector_type(8))) unsigned short us8;
typedef unsigned short us;

__device__ inline us f2h(float f) {
    union { _Float16 h; us u; } x;
    x.h = (_Float16)f;   // RTE
    return x.u;
}
__device__ inline float h2f(us u) {
    union { us u; _Float16 h; } x; x.u = u;
    return (float)x.h;
}

__device__ inline void gload16(const us* g, us* l) {
    __builtin_amdgcn_global_load_lds(
        (const __attribute__((address_space(1))) unsigned int*)g,
        (__attribute__((address_space(3))) unsigned int*)l, 16, 0, 0);
}

// ---------------------------------------------------------------------------
// Split cast: f32 -> hi fp16 (+ lo fp16 residual if DO_LO). 4 elems/thread.
// ---------------------------------------------------------------------------
template<int DO_LO>
__global__ __launch_bounds__(256)
void cast2_k(const float* __restrict__ in, us* __restrict__ hi, us* __restrict__ lo) {
    const size_t i = ((size_t)blockIdx.x * 256 + threadIdx.x) * 4;
    const float4 v = *(const float4*)&in[i];
    ushort4 h;
    h.x = f2h(v.x); h.y = f2h(v.y); h.z = f2h(v.z); h.w = f2h(v.w);
    *(ushort4*)&hi[i] = h;
    if (DO_LO) {
        ushort4 l;
        l.x = f2h(v.x - h2f(h.x)); l.y = f2h(v.y - h2f(h.y));
        l.z = f2h(v.z - h2f(h.z)); l.w = f2h(v.w - h2f(h.w));
        *(ushort4*)&lo[i] = l;
    }
}

// ---------------------------------------------------------------------------
// Weight transpose + split cast: W fp32 [K][N] -> Wt1(,Wt2) fp16 [N][K].
// ---------------------------------------------------------------------------
template<int DO_LO>
__global__ __launch_bounds__(256)
void wsplit_k(const float* __restrict__ W, us* __restrict__ Wt1, us* __restrict__ Wt2) {
    __shared__ float t[64][65];
    const int tid = threadIdx.x;
    const int k0 = blockIdx.x*64, n0 = blockIdx.y*64;
    #pragma unroll
    for (int i = 0; i < 4; ++i) {
        const int c = i*256 + tid;
        const int row = c >> 4, col = (c & 15) * 4;
        const float4 v = *(const float4*)&W[(size_t)(k0+row)*D_ + n0+col];
        t[row][col]=v.x; t[row][col+1]=v.y; t[row][col+2]=v.z; t[row][col+3]=v.w;
    }
    __syncthreads();
    #pragma unroll
    for (int i = 0; i < 4; ++i) {
        const int c = i*256 + tid;
        const int n = c >> 4, k = (c & 15) * 4;
        float f[4] = { t[k][n], t[k+1][n], t[k+2][n], t[k+3][n] };
        ushort4 h;
        h.x=f2h(f[0]); h.y=f2h(f[1]); h.z=f2h(f[2]); h.w=f2h(f[3]);
        *(ushort4*)&Wt1[(size_t)(n0+n)*D_ + k0+k] = h;
        if (DO_LO) {
            ushort4 l;
            l.x=f2h(f[0]-h2f(h.x)); l.y=f2h(f[1]-h2f(h.y));
            l.z=f2h(f[2]-h2f(h.z)); l.w=f2h(f[3]-h2f(h.w));
            *(ushort4*)&Wt2[(size_t)(n0+n)*D_ + k0+k] = l;
        }
    }
}

// ---------------------------------------------------------------------------
// V transpose: fp16 [b][s][d] -> fp16 [b][d][s]
// ---------------------------------------------------------------------------
__global__ __launch_bounds__(256)
void vtrans_k(const us* __restrict__ V, us* __restrict__ Vt) {
    __shared__ us t[64][68];
    const int tid = threadIdx.x;
    const int s0 = blockIdx.x*64, d0 = blockIdx.y*64, b = blockIdx.z;
    const us* Vb  = V  + (size_t)b*S_*D_;
    us*       Vtb = Vt + (size_t)b*D_*S_;
    #pragma unroll
    for (int i = 0; i < 4; ++i) {
        const int c = i*256 + tid;
        const int row = c >> 4, col = (c & 15) * 4;
        *(ushort4*)&t[row][col] = *(const ushort4*)&Vb[(size_t)(s0+row)*D_ + d0+col];
    }
    __syncthreads();
    #pragma unroll
    for (int i = 0; i < 4; ++i) {
        const int c = i*256 + tid;
        const int d = c >> 4, s = (c & 15) * 4;
        ushort4 o;
        o.x = t[s][d]; o.y = t[s+1][d]; o.z = t[s+2][d]; o.w = t[s+3][d];
        *(ushort4*)&Vtb[(size_t)(d0+d)*S_ + s0+s] = o;
    }
}

// ---------------------------------------------------------------------------
// fp16 MFMA GEMM: C[M][N] = A[M][K] @ Bt[N][K]^T, fp32 accumulate.
// 128x128 tile, BK=64, 4 waves 2x2, global_load_lds width-16 staging.
// blockIdx.x = M-tile (XCD = blk%8 = m%8 -> A-panel L2 sharing on one XCD).
// SPLIT=1: A=A1+A2, B=B1+B2 (fp16 hi/lo); computes A1B1+A1B2+A2B1 (fp32-grade).
// EPI: 0 = fp32 store; 1 = f16(acc+bias); 2 = f16(cos(acc+bias));
//      3 = split f16 store of (acc+bias) into C,C2.
// Epilogue is LDS-staged so all global stores are 16B/lane coalesced
// (raw C/D-layout scatter cost 573 MB WRITE_SIZE in round 4).
// ---------------------------------------------------------------------------
template<int Nv, int Kv, int SPLIT, int EPI>
__global__ __launch_bounds__(256)
void gemm_bt_k(const us* __restrict__ A1, const us* __restrict__ A2,
               const us* __restrict__ B1, const us* __restrict__ B2,
               const float* __restrict__ bias, void* __restrict__ Cv,
               us* __restrict__ C2, long sA, long sB, long sC) {
    __shared__ us smem[(SPLIT?4:2)*128*64];
    us* As  = smem;                              // (+As2 if SPLIT)
    us* As2 = smem + 128*64;
    us* Bs  = smem + (SPLIT?2:1)*128*64;
    us* Bs2 = Bs + 128*64;
    const int tid = threadIdx.x;
    const us* A1b = A1 + (size_t)blockIdx.z * sA;
    const us* A2b = SPLIT ? A2 + (size_t)blockIdx.z * sA : nullptr;
    const us* B1b = B1 + (size_t)blockIdx.z * sB;
    const us* B2b = SPLIT ? B2 + (size_t)blockIdx.z * sB : nullptr;
    const int m0 = blockIdx.x * 128, n0 = blockIdx.y * 128;   // m on x: XCD swizzle
    const int lane = tid & 63, w = tid >> 6;
    const int mw = (w >> 1) * 64, nw = (w & 1) * 64;
    const int lr = lane & 15, lq = lane >> 4;

    const int crow = tid >> 3;          // staging row (0..31, +32/i)
    const int ccol = (tid & 7) * 8;     // staging col chunk (elems)

    f32x4 acc[4][4];
    #pragma unroll
    for (int i = 0; i < 4; ++i)
        #pragma unroll
        for (int j = 0; j < 4; ++j)
            acc[i][j] = (f32x4){0.f, 0.f, 0.f, 0.f};

    for (int kc = 0; kc < Kv; kc += 64) {
        #pragma unroll
        for (int i = 0; i < 4; ++i) {
            const int r = crow + i * 32;
            gload16(&A1b[(size_t)(m0 + r) * Kv + kc + ccol], &As[(size_t)(i*256 + tid) * 8]);
            gload16(&B1b[(size_t)(n0 + r) * Kv + kc + ccol], &Bs[(size_t)(i*256 + tid) * 8]);
            if (SPLIT) {
                gload16(&A2b[(size_t)(m0 + r) * Kv + kc + ccol], &As2[(size_t)(i*256 + tid) * 8]);
                gload16(&B2b[(size_t)(n0 + r) * Kv + kc + ccol], &Bs2[(size_t)(i*256 + tid) * 8]);
            }
        }
        __syncthreads();
        #pragma unroll
        for (int kk = 0; kk < 64; kk += 32) {
            f16x8 a1[4], b1[4];
            #pragma unroll
            for (int i = 0; i < 4; ++i)
                a1[i] = *(const f16x8*)&As[(mw + i*16 + lr) * 64 + kk + lq*8];
            #pragma unroll
            for (int j = 0; j < 4; ++j)
                b1[j] = *(const f16x8*)&Bs[(nw + j*16 + lr) * 64 + kk + lq*8];
            if (SPLIT) {
                f16x8 a2[4], b2[4];
                #pragma unroll
                for (int i = 0; i < 4; ++i)
                    a2[i] = *(const f16x8*)&As2[(mw + i*16 + lr) * 64 + kk + lq*8];
                #pragma unroll
                for (int j = 0; j < 4; ++j)
                    b2[j] = *(const f16x8*)&Bs2[(nw + j*16 + lr) * 64 + kk + lq*8];
                #pragma unroll
                for (int i = 0; i < 4; ++i)
                    #pragma unroll
                    for (int j = 0; j < 4; ++j) {
                        acc[i][j] = __builtin_amdgcn_mfma_f32_16x16x32_f16(a2[i], b1[j], acc[i][j], 0, 0, 0);
                        acc[i][j] = __builtin_amdgcn_mfma_f32_16x16x32_f16(a1[i], b2[j], acc[i][j], 0, 0, 0);
                        acc[i][j] = __builtin_amdgcn_mfma_f32_16x16x32_f16(a1[i], b1[j], acc[i][j], 0, 0, 0);
                    }
            } else {
                #pragma unroll
                for (int i = 0; i < 4; ++i)
                    #pragma unroll
                    for (int j = 0; j < 4; ++j)
                        acc[i][j] = __builtin_amdgcn_mfma_f32_16x16x32_f16(a1[i], b1[j], acc[i][j], 0, 0, 0);
            }
        }
        __syncthreads();
    }

    // ---------------- coalesced epilogue ----------------
    // Wave w owns quadrant rows [mw,mw+64) x cols [nw,nw+64). Stage 32 rows
    // at a time (per-wave 8 KB slab in the first 32 KB of smem), read back
    // row-major, store 16B/lane contiguous.
    float* slab = (float*)smem + (size_t)w * 2048;   // 32x64 fp32
    const int lrow0 = lane >> 3, cb = (lane & 7) * 8;
    #pragma unroll
    for (int p = 0; p < 2; ++p) {
        #pragma unroll
        for (int ii = 0; ii < 2; ++ii) {
            const int i = p*2 + ii;
            #pragma unroll
            for (int j = 0; j < 4; ++j)
                #pragma unroll
                for (int r = 0; r < 4; ++r)
                    slab[(ii*16 + lq*4 + r)*64 + j*16 + lr] = acc[i][j][r];
        }
        __syncthreads();
        #pragma unroll
        for (int t = 0; t < 4; ++t) {
            const int lrow = t*8 + lrow0;
            const int grow = m0 + mw + p*32 + lrow;
            const int gcol = n0 + nw + cb;
            const size_t idx = (size_t)grow * Nv + gcol;
            float v[8];
            #pragma unroll
            for (int u = 0; u < 8; ++u) v[u] = slab[lrow*64 + cb + u];
            if (EPI == 0) {
                float* Cf = (float*)Cv + (size_t)blockIdx.z * sC;
                float4 o0 = {v[0],v[1],v[2],v[3]}, o1 = {v[4],v[5],v[6],v[7]};
                *(float4*)&Cf[idx] = o0;
                *(float4*)&Cf[idx+4] = o1;
            } else if (EPI == 1 || EPI == 2) {
                us8 o;
                #pragma unroll
                for (int u = 0; u < 8; ++u) {
                    const float tv = v[u] + bias[gcol + u];
                    o[u] = f2h(EPI == 2 ? cosf(tv) : tv);
                }
                *(us8*)&((us*)Cv)[idx] = o;
            } else {
                us8 oh, ol;
                #pragma unroll
                for (int u = 0; u < 8; ++u) {
                    const float tv = v[u] + bias[gcol + u];
                    const us hh = f2h(tv);
                    oh[u] = hh;
                    ol[u] = f2h(tv - h2f(hh));
                }
                *(us8*)&((us*)Cv)[idx] = oh;
                *(us8*)&C2[idx] = ol;
            }
        }
        __syncthreads();
    }
}

// ---------------------------------------------------------------------------
// Row softmax: S fp32 [S_] per row -> normalized P fp16. One block per row.
// ---------------------------------------------------------------------------
__global__ __launch_bounds__(256)
void softmax_k(const float* __restrict__ S, us* __restrict__ P) {
    __shared__ float red[8];
    const int tid = threadIdx.x;
    const int lane = tid & 63, w = tid >> 6;
    const float* row = S + (size_t)blockIdx.x * S_;

    const float4 v0 = *(const float4*)&row[tid*8];
    const float4 v1 = *(const float4*)&row[tid*8 + 4];
    float e[8] = {v0.x, v0.y, v0.z, v0.w, v1.x, v1.y, v1.z, v1.w};

    float mx = e[0];
    #pragma unroll
    for (int j = 1; j < 8; ++j) mx = fmaxf(mx, e[j]);
    #pragma unroll
    for (int off = 1; off < 64; off <<= 1) mx = fmaxf(mx, __shfl_xor(mx, off));
    if (lane == 0) red[w] = mx;
    __syncthreads();
    mx = fmaxf(fmaxf(red[0], red[1]), fmaxf(red[2], red[3]));

    float sum = 0.f;
    #pragma unroll
    for (int j = 0; j < 8; ++j) { e[j] = __expf(e[j] - mx); sum += e[j]; }
    #pragma unroll
    for (int off = 1; off < 64; off <<= 1) sum += __shfl_xor(sum, off);
    if (lane == 0) red[4 + w] = sum;
    __syncthreads();
    const float inv = 1.0f / (red[4] + red[5] + red[6] + red[7]);

    us8 o;
    #pragma unroll
    for (int j = 0; j < 8; ++j) o[j] = f2h(e[j] * inv);
    *(us8*)&P[(size_t)blockIdx.x * S_ + tid*8] = o;
}

// ---------------------------------------------------------------------------
extern "C" void kernel_launch(void* const* d_in, const int* in_sizes, int n_in,
                              void* d_out, int out_size, void* d_ws, size_t ws_size,
                              hipStream_t stream) {
    const float* x  = (const float*)d_in[0];
    const float* y  = (const float*)d_in[1];
    const float* Wq = (const float*)d_in[2];
    const float* bq = (const float*)d_in[3];
    const float* Wk = (const float*)d_in[4];
    const float* bk = (const float*)d_in[5];
    const float* Wv = (const float*)d_in[6];
    const float* bv = (const float*)d_in[7];
    const float* Wr = (const float*)d_in[8];
    const float* br = (const float*)d_in[9];
    float* out = (float*)d_out;

    // Workspace choreography (96 MB, proven size). Regions by phase:
    //  [ 0,16) K1            -> Vt
    //  [16,32) Wk1/Wk2, then Wr1/Wr2 -> xh -> Vh -> P(b0,b1)
    //  [32,48) y1                              -> P(b2,b3)
    //  [48,64) K2            -> Q
    //  [64,80) Kh
    //  [80,96) y2 -> Wq1/Wv1 -> S (per batch fp32)
    char* wsb = (char*)d_ws;
    us*    K1  = (us*)(wsb +  0*MBYTE);
    us*    Vt  = (us*)(wsb +  0*MBYTE);
    us*    Wk1 = (us*)(wsb + 16*MBYTE);
    us*    Wk2 = (us*)(wsb + 18*MBYTE);
    us*    Wr1 = (us*)(wsb + 16*MBYTE);
    us*    Wr2 = (us*)(wsb + 18*MBYTE);
    us*    xh  = (us*)(wsb + 16*MBYTE);
    us*    Vh  = (us*)(wsb + 16*MBYTE);
    us*    Pb  = (us*)(wsb + 16*MBYTE);
    us*    y1  = (us*)(wsb + 32*MBYTE);
    us*    K2  = (us*)(wsb + 48*MBYTE);
    us*    Qb  = (us*)(wsb + 48*MBYTE);
    us*    Kh  = (us*)(wsb + 64*MBYTE);
    us*    y2  = (us*)(wsb + 80*MBYTE);
    us*    Wq1 = (us*)(wsb + 80*MBYTE);
    us*    Wv1 = (us*)(wsb + 80*MBYTE);
    float* Sb  = (float*)(wsb + 80*MBYTE);

    const dim3 bb(256);
    const dim3 gcast(M_*D_/1024), gw(16,16);
    const dim3 gproj(M_/128, D_/128);            // m on x -> XCD A-panel sharing

    // --- K chain (split-fp16 = fp32-grade accuracy) ---
    cast2_k<1><<<gcast, bb, 0, stream>>>(y, y1, y2);
    wsplit_k<1><<<gw, bb, 0, stream>>>(Wk, Wk1, Wk2);
    gemm_bt_k<D_, D_, 1, 3><<<gproj, bb, 0, stream>>>(
        y1, y2, Wk1, Wk2, bk, (void*)K1, K2, 0, 0, 0);
    wsplit_k<1><<<gw, bb, 0, stream>>>(Wr, Wr1, Wr2);
    gemm_bt_k<D_, D_, 1, 2><<<gproj, bb, 0, stream>>>(
        K1, K2, Wr1, Wr2, br, (void*)Kh, nullptr, 0, 0, 0);

    // --- Q, V (plain fp16 MFMA) ---
    cast2_k<0><<<gcast, bb, 0, stream>>>(x, xh, nullptr);
    wsplit_k<0><<<gw, bb, 0, stream>>>(Wq, Wq1, nullptr);
    gemm_bt_k<D_, D_, 0, 1><<<gproj, bb, 0, stream>>>(
        xh, nullptr, Wq1, nullptr, bq, (void*)Qb, nullptr, 0, 0, 0);
    wsplit_k<0><<<gw, bb, 0, stream>>>(Wv, Wv1, nullptr);
    gemm_bt_k<D_, D_, 0, 1><<<gproj, bb, 0, stream>>>(
        y1, nullptr, Wv1, nullptr, bv, (void*)Vh, nullptr, 0, 0, 0);
    vtrans_k<<<dim3(S_/64, D_/64, B_), bb, 0, stream>>>(Vh, Vt);

    // --- attention core ---
    for (int b = 0; b < B_; ++b) {
        gemm_bt_k<S_, D_, 0, 0><<<dim3(S_/128, S_/128, 1), bb, 0, stream>>>(
            Qb + (size_t)b*S_*D_, nullptr, Kh + (size_t)b*S_*D_, nullptr,
            nullptr, (void*)Sb, nullptr, 0, 0, 0);
        softmax_k<<<dim3(S_), bb, 0, stream>>>(Sb, Pb + (size_t)b*S_*S_);
    }
    gemm_bt_k<D_, S_, 0, 0><<<dim3(S_/128, D_/128, B_), bb, 0, stream>>>(
        Pb, nullptr, Vt, nullptr, nullptr, (void*)out, nullptr,
        (long)S_*S_, (long)D_*S_, (long)S_*D_);
}